// Round 1
// baseline (3258.281 us; speedup 1.0000x reference)
//
#include <hip/hip_runtime.h>
#include <hip/hip_bf16.h>
#include <stdint.h>

#define Bb 4
#define Dd 128
#define Nn 16384
#define Ee 65536

typedef __attribute__((ext_vector_type(4))) float f32x4;
typedef __attribute__((ext_vector_type(8))) short s16x8;

__device__ __forceinline__ unsigned short f2bf(float f) {
  union { float f; unsigned int u; } v; v.f = f;
  unsigned int r = v.u + 0x7fffu + ((v.u >> 16) & 1u);
  return (unsigned short)(r >> 16);
}

// ---- fold BN into weights, convert to bf16 ----
__global__ void prep_weights(const float* __restrict__ w1, const float* __restrict__ b1,
                             const float* __restrict__ g, const float* __restrict__ beta,
                             const float* __restrict__ mu, const float* __restrict__ var,
                             const float* __restrict__ w2,
                             unsigned short* __restrict__ W1s, unsigned short* __restrict__ W2s,
                             float* __restrict__ c1) {
  int i = blockIdx.x * 256 + threadIdx.x;
  if (i < 256 * 384) {
    int o = i / 384;
    float scale = g[o] * rsqrtf(var[o] + 1e-5f);
    W1s[i] = f2bf(w1[i] * scale);
  }
  if (i < 128 * 256) W2s[i] = f2bf(w2[i]);
  if (i < 256) {
    float scale = g[i] * rsqrtf(var[i] + 1e-5f);
    c1[i] = b1[i] * scale + beta[i] - mu[i] * scale;
  }
}

// ---- transpose ldesc [B][D][N] f32 -> [B][N][D] bf16 (both sides) ----
__global__ void transpose_ldesc(const float* __restrict__ l0, const float* __restrict__ l1,
                                unsigned short* __restrict__ t0, unsigned short* __restrict__ t1) {
  __shared__ float tile[32][33];
  int n0 = blockIdx.x * 32;
  int d0 = blockIdx.y * 32;
  int zb = blockIdx.z;
  int side = zb >> 2, b = zb & 3;
  const float* src = (side ? l1 : l0) + (size_t)b * Dd * Nn;
  unsigned short* dst = (side ? t1 : t0) + (size_t)b * Nn * Dd;
  int tx = threadIdx.x, ty = threadIdx.y;
#pragma unroll
  for (int i = 0; i < 4; ++i)
    tile[ty + i * 8][tx] = src[(size_t)(d0 + ty + i * 8) * Nn + n0 + tx];
  __syncthreads();
#pragma unroll
  for (int i = 0; i < 4; ++i) {
    int r = ty + i * 8;
    dst[(size_t)(n0 + r) * Dd + d0 + tx] = f2bf(tile[tx][r]);
  }
}

// ---- per-junction line counts (float, exact for small ints) ----
__global__ void count_kernel(const int* __restrict__ idx0, const int* __restrict__ idx1,
                             float* __restrict__ cnt) {
  int i = blockIdx.x * 256 + threadIdx.x;   // 0 .. 2*B*E-1
  int side = i >> 18;                       // B*E = 262144 = 2^18
  int rem = i & (262143);
  int b = rem >> 16;                        // E = 65536
  int e = rem & 65535;
  const int* jx = side ? idx1 : idx0;
  int n = jx[b * Ee + e];
  unsafeAtomicAdd(&cnt[((size_t)side * Bb + b) * Nn + n], 1.0f);
}

#define XSTRIDE 392   // bf16 elems; 784 B row pitch, 16B-aligned, bank-friendly
#define HSTRIDE 264   // bf16 elems; 528 B row pitch

__global__ __launch_bounds__(256) void fused_line_mlp(
    const unsigned short* __restrict__ ldescT0, const unsigned short* __restrict__ ldescT1,
    const float* __restrict__ enc0, const float* __restrict__ enc1,
    const int* __restrict__ idx0, const int* __restrict__ idx1,
    const unsigned short* __restrict__ W1s, const unsigned short* __restrict__ W2s,
    const float* __restrict__ c1, const float* __restrict__ b2,
    float* __restrict__ outacc) {
  __shared__ unsigned short smem[64 * XSTRIDE];  // 50176 B; X tile, later aliased as H tile
  __shared__ int idx_s[64];

  const int b = blockIdx.y;
  const int side = blockIdx.z;
  const int e0 = blockIdx.x * 64;
  const unsigned short* ldescT = side ? ldescT1 : ldescT0;
  const float* enc = side ? enc1 : enc0;
  const int* jx = side ? idx1 : idx0;
  float* accout = outacc + ((size_t)side * Bb + b) * Dd * Nn;

  const int t = threadIdx.x;
  if (t < 64) idx_s[t] = jx[(size_t)b * Ee + e0 + t];
  __syncthreads();

  // ---- stage X = [desc(128); flipped(128); enc(128)] for 64 columns, bf16, col-major ----
  {
    int j = t >> 2, p = t & 3;
    int i0 = idx_s[j], i1 = idx_s[j ^ 1];
    const uint4* s0 = (const uint4*)(ldescT + ((size_t)b * Nn + i0) * Dd + p * 32);
    const uint4* s1 = (const uint4*)(ldescT + ((size_t)b * Nn + i1) * Dd + p * 32);
    uint4* dst0 = (uint4*)&smem[j * XSTRIDE + p * 32];
    uint4* dst1 = (uint4*)&smem[j * XSTRIDE + 128 + p * 32];
#pragma unroll
    for (int q = 0; q < 4; ++q) dst0[q] = s0[q];
#pragma unroll
    for (int q = 0; q < 4; ++q) dst1[q] = s1[q];
  }
  {
    int j = t & 63, dg = t >> 6;
    const float* src = enc + ((size_t)b * Dd + dg * 32) * Ee + e0 + j;
    unsigned int* dst = (unsigned int*)&smem[j * XSTRIDE + 256 + dg * 32];
#pragma unroll
    for (int d2 = 0; d2 < 32; d2 += 2) {
      float f0 = src[(size_t)d2 * Ee];
      float f1 = src[(size_t)(d2 + 1) * Ee];
      dst[d2 >> 1] = (unsigned int)f2bf(f0) | ((unsigned int)f2bf(f1) << 16);
    }
  }
  __syncthreads();

  const int w = t >> 6;          // wave 0..3
  const int lr = t & 15;         // row/col within 16-tile
  const int lk = (t & 63) >> 4;  // k-group 0..3

  // ---- GEMM1: H[256,64] = W1s[256,384] * X[384,64] ----
  f32x4 acc[4][4] = {};
#pragma unroll
  for (int ks = 0; ks < 12; ++ks) {
    int k0 = ks * 32;
    s16x8 bfrag[4];
#pragma unroll
    for (int ct = 0; ct < 4; ++ct)
      bfrag[ct] = *(const s16x8*)&smem[(ct * 16 + lr) * XSTRIDE + k0 + lk * 8];
#pragma unroll
    for (int rt = 0; rt < 4; ++rt) {
      const s16x8 afrag = *(const s16x8*)&W1s[(size_t)(w * 64 + rt * 16 + lr) * 384 + k0 + lk * 8];
#pragma unroll
      for (int ct = 0; ct < 4; ++ct)
        acc[rt][ct] = __builtin_amdgcn_mfma_f32_16x16x32_bf16(afrag, bfrag[ct], acc[rt][ct], 0, 0, 0);
    }
  }
  __syncthreads();  // all X reads done -> smem may be reused as H

  // ---- bias + ReLU -> H bf16 in LDS (col-major) ----
#pragma unroll
  for (int rt = 0; rt < 4; ++rt) {
    int rowbase = w * 64 + rt * 16 + lk * 4;
    float c1v[4];
#pragma unroll
    for (int r = 0; r < 4; ++r) c1v[r] = c1[rowbase + r];
#pragma unroll
    for (int ct = 0; ct < 4; ++ct) {
      int col = ct * 16 + lr;
      float v0 = fmaxf(acc[rt][ct][0] + c1v[0], 0.f);
      float v1 = fmaxf(acc[rt][ct][1] + c1v[1], 0.f);
      float v2 = fmaxf(acc[rt][ct][2] + c1v[2], 0.f);
      float v3 = fmaxf(acc[rt][ct][3] + c1v[3], 0.f);
      unsigned int p0 = (unsigned int)f2bf(v0) | ((unsigned int)f2bf(v1) << 16);
      unsigned int p1 = (unsigned int)f2bf(v2) | ((unsigned int)f2bf(v3) << 16);
      *(uint2*)&smem[col * HSTRIDE + rowbase] = make_uint2(p0, p1);
    }
  }
  __syncthreads();

  // ---- GEMM2: U[128,64] = W2s[128,256] * H[256,64] ----
  f32x4 acc2[2][4] = {};
#pragma unroll
  for (int ks = 0; ks < 8; ++ks) {
    int k0 = ks * 32;
    s16x8 bfrag[4];
#pragma unroll
    for (int ct = 0; ct < 4; ++ct)
      bfrag[ct] = *(const s16x8*)&smem[(ct * 16 + lr) * HSTRIDE + k0 + lk * 8];
#pragma unroll
    for (int rt = 0; rt < 2; ++rt) {
      const s16x8 afrag = *(const s16x8*)&W2s[(size_t)(w * 32 + rt * 16 + lr) * 256 + k0 + lk * 8];
#pragma unroll
      for (int ct = 0; ct < 4; ++ct)
        acc2[rt][ct] = __builtin_amdgcn_mfma_f32_16x16x32_bf16(afrag, bfrag[ct], acc2[rt][ct], 0, 0, 0);
    }
  }

  // ---- epilogue: + b2, scatter-add into accumulator (d_out) ----
#pragma unroll
  for (int rt = 0; rt < 2; ++rt) {
    int rowbase = w * 32 + rt * 16 + lk * 4;
    float b2v[4];
#pragma unroll
    for (int r = 0; r < 4; ++r) b2v[r] = b2[rowbase + r];
#pragma unroll
    for (int ct = 0; ct < 4; ++ct) {
      int col = ct * 16 + lr;
      int n = idx_s[col];
#pragma unroll
      for (int r = 0; r < 4; ++r) {
        float v = acc2[rt][ct][r] + b2v[r];
        unsafeAtomicAdd(&accout[(size_t)(rowbase + r) * Nn + n], v);
      }
    }
  }
}

// ---- out = ldesc + acc/max(cnt,1), in place over d_out ----
__global__ void finalize_kernel(const float* __restrict__ l0, const float* __restrict__ l1,
                                const float* __restrict__ cnt, float* __restrict__ out) {
  size_t i = (size_t)blockIdx.x * 256 + threadIdx.x;  // over 2*B*D*N/4
  size_t base = i * 4;
  int n = (int)(base & (Nn - 1));
  size_t sbd = base >> 14;           // / N
  int d = (int)(sbd & (Dd - 1));
  int sb = (int)(sbd >> 7);          // side*B + b, 0..7
  int side = sb >> 2, b = sb & 3;
  const float* l = (side ? l1 : l0) + ((size_t)b * Dd + d) * Nn + n;
  float4 a = *(const float4*)&out[base];
  float4 c = *(const float4*)&cnt[(size_t)sb * Nn + n];
  float4 lv = *(const float4*)l;
  float4 r;
  r.x = lv.x + a.x / fmaxf(c.x, 1.f);
  r.y = lv.y + a.y / fmaxf(c.y, 1.f);
  r.z = lv.z + a.z / fmaxf(c.z, 1.f);
  r.w = lv.w + a.w / fmaxf(c.w, 1.f);
  *(float4*)&out[base] = r;
}

extern "C" void kernel_launch(void* const* d_in, const int* in_sizes, int n_in,
                              void* d_out, int out_size, void* d_ws, size_t ws_size,
                              hipStream_t stream) {
  const float* ldesc0 = (const float*)d_in[0];
  const float* ldesc1 = (const float*)d_in[1];
  const float* enc0   = (const float*)d_in[2];
  const float* enc1   = (const float*)d_in[3];
  const int*   idx0   = (const int*)d_in[4];
  const int*   idx1   = (const int*)d_in[5];
  const float* w1     = (const float*)d_in[6];
  const float* b1     = (const float*)d_in[7];
  const float* g      = (const float*)d_in[8];
  const float* beta   = (const float*)d_in[9];
  const float* mu     = (const float*)d_in[10];
  const float* var    = (const float*)d_in[11];
  const float* w2     = (const float*)d_in[12];
  const float* b2     = (const float*)d_in[13];
  float* out = (float*)d_out;

  char* ws = (char*)d_ws;
  size_t off = 0;
  unsigned short* t0 = (unsigned short*)(ws + off); off += (size_t)Bb * Nn * Dd * 2;
  unsigned short* t1 = (unsigned short*)(ws + off); off += (size_t)Bb * Nn * Dd * 2;
  unsigned short* W1s = (unsigned short*)(ws + off); off += 256 * 384 * 2;
  unsigned short* W2s = (unsigned short*)(ws + off); off += 128 * 256 * 2;
  float* c1 = (float*)(ws + off); off += 256 * 4;
  float* cnt = (float*)(ws + off); off += (size_t)2 * Bb * Nn * 4;

  hipMemsetAsync(out, 0, (size_t)2 * Bb * Dd * Nn * 4, stream);
  hipMemsetAsync(cnt, 0, (size_t)2 * Bb * Nn * 4, stream);

  prep_weights<<<384, 256, 0, stream>>>(w1, b1, g, beta, mu, var, w2, W1s, W2s, c1);
  transpose_ldesc<<<dim3(Nn / 32, Dd / 32, 8), dim3(32, 8), 0, stream>>>(ldesc0, ldesc1, t0, t1);
  count_kernel<<<2048, 256, 0, stream>>>(idx0, idx1, cnt);
  fused_line_mlp<<<dim3(Ee / 64, Bb, 2), 256, 0, stream>>>(t0, t1, enc0, enc1, idx0, idx1,
                                                           W1s, W2s, c1, b2, out);
  finalize_kernel<<<16384, 256, 0, stream>>>(ldesc0, ldesc1, cnt, out);
}

// Round 2
// 1005.136 us; speedup vs baseline: 3.2416x; 3.2416x over previous
//
#include <hip/hip_runtime.h>
#include <hip/hip_bf16.h>
#include <stdint.h>

#define Bb 4
#define Dd 128
#define Nn 16384
#define Ee 65536

typedef __attribute__((ext_vector_type(4))) float f32x4;
typedef __attribute__((ext_vector_type(8))) short s16x8;

__device__ __forceinline__ unsigned short f2bf(float f) {
  union { float f; unsigned int u; } v; v.f = f;
  unsigned int r = v.u + 0x7fffu + ((v.u >> 16) & 1u);
  return (unsigned short)(r >> 16);
}

// ---- fold BN into weights, convert to bf16 ----
__global__ void prep_weights(const float* __restrict__ w1, const float* __restrict__ b1,
                             const float* __restrict__ g, const float* __restrict__ beta,
                             const float* __restrict__ mu, const float* __restrict__ var,
                             const float* __restrict__ w2,
                             unsigned short* __restrict__ W1s, unsigned short* __restrict__ W2s,
                             float* __restrict__ c1) {
  int i = blockIdx.x * 256 + threadIdx.x;
  if (i < 256 * 384) {
    int o = i / 384;
    float scale = g[o] * rsqrtf(var[o] + 1e-5f);
    W1s[i] = f2bf(w1[i] * scale);
  }
  if (i < 128 * 256) W2s[i] = f2bf(w2[i]);
  if (i < 256) {
    float scale = g[i] * rsqrtf(var[i] + 1e-5f);
    c1[i] = b1[i] * scale + beta[i] - mu[i] * scale;
  }
}

// ---- transpose ldesc [B][D][N] f32 -> [B][N][D] bf16 (both sides) ----
__global__ void transpose_ldesc(const float* __restrict__ l0, const float* __restrict__ l1,
                                unsigned short* __restrict__ t0, unsigned short* __restrict__ t1) {
  __shared__ float tile[32][33];
  int n0 = blockIdx.x * 32;
  int d0 = blockIdx.y * 32;
  int zb = blockIdx.z;
  int side = zb >> 2, b = zb & 3;
  const float* src = (side ? l1 : l0) + (size_t)b * Dd * Nn;
  unsigned short* dst = (side ? t1 : t0) + (size_t)b * Nn * Dd;
  int tx = threadIdx.x, ty = threadIdx.y;
#pragma unroll
  for (int i = 0; i < 4; ++i)
    tile[ty + i * 8][tx] = src[(size_t)(d0 + ty + i * 8) * Nn + n0 + tx];
  __syncthreads();
#pragma unroll
  for (int i = 0; i < 4; ++i) {
    int r = ty + i * 8;
    dst[(size_t)(n0 + r) * Dd + d0 + tx] = f2bf(tile[tx][r]);
  }
}

// ---- per-junction line counts (float, exact for small ints) ----
__global__ void count_kernel(const int* __restrict__ idx0, const int* __restrict__ idx1,
                             float* __restrict__ cnt) {
  int i = blockIdx.x * 256 + threadIdx.x;   // 0 .. 2*B*E-1
  int side = i >> 18;                       // B*E = 262144 = 2^18
  int rem = i & (262143);
  int b = rem >> 16;                        // E = 65536
  int e = rem & 65535;
  const int* jx = side ? idx1 : idx0;
  int n = jx[b * Ee + e];
  unsafeAtomicAdd(&cnt[((size_t)side * Bb + b) * Nn + n], 1.0f);
}

#define XSTRIDE 392   // bf16 elems; 784 B row pitch, 16B-aligned, bank-friendly
#define HSTRIDE 264   // bf16 elems; 528 B row pitch

// COAL=true: accumulator laid out [side][b][n][d] (coalesced atomics, ws)
// COAL=false: accumulator [side][b][d][n] directly in d_out (legacy fallback)
template <bool COAL>
__global__ __launch_bounds__(256) void fused_line_mlp(
    const unsigned short* __restrict__ ldescT0, const unsigned short* __restrict__ ldescT1,
    const float* __restrict__ enc0, const float* __restrict__ enc1,
    const int* __restrict__ idx0, const int* __restrict__ idx1,
    const unsigned short* __restrict__ W1s, const unsigned short* __restrict__ W2s,
    const float* __restrict__ c1, const float* __restrict__ b2,
    float* __restrict__ outacc) {
  __shared__ unsigned short smem[64 * XSTRIDE];  // 50176 B; X tile, later aliased as H tile
  __shared__ int idx_s[64];

  const int b = blockIdx.y;
  const int side = blockIdx.z;
  const int e0 = blockIdx.x * 64;
  const unsigned short* ldescT = side ? ldescT1 : ldescT0;
  const float* enc = side ? enc1 : enc0;
  const int* jx = side ? idx1 : idx0;
  float* accout = outacc + ((size_t)side * Bb + b) * Dd * Nn;

  const int t = threadIdx.x;
  if (t < 64) idx_s[t] = jx[(size_t)b * Ee + e0 + t];
  __syncthreads();

  // ---- stage X = [desc(128); flipped(128); enc(128)] for 64 columns, bf16, col-major ----
  {
    int j = t >> 2, p = t & 3;
    int i0 = idx_s[j], i1 = idx_s[j ^ 1];
    const uint4* s0 = (const uint4*)(ldescT + ((size_t)b * Nn + i0) * Dd + p * 32);
    const uint4* s1 = (const uint4*)(ldescT + ((size_t)b * Nn + i1) * Dd + p * 32);
    uint4* dst0 = (uint4*)&smem[j * XSTRIDE + p * 32];
    uint4* dst1 = (uint4*)&smem[j * XSTRIDE + 128 + p * 32];
#pragma unroll
    for (int q = 0; q < 4; ++q) dst0[q] = s0[q];
#pragma unroll
    for (int q = 0; q < 4; ++q) dst1[q] = s1[q];
  }
  {
    int j = t & 63, dg = t >> 6;
    const float* src = enc + ((size_t)b * Dd + dg * 32) * Ee + e0 + j;
    unsigned int* dst = (unsigned int*)&smem[j * XSTRIDE + 256 + dg * 32];
#pragma unroll
    for (int d2 = 0; d2 < 32; d2 += 2) {
      float f0 = src[(size_t)d2 * Ee];
      float f1 = src[(size_t)(d2 + 1) * Ee];
      dst[d2 >> 1] = (unsigned int)f2bf(f0) | ((unsigned int)f2bf(f1) << 16);
    }
  }
  __syncthreads();

  const int w = t >> 6;          // wave 0..3
  const int lr = t & 15;         // row/col within 16-tile
  const int lk = (t & 63) >> 4;  // k-group 0..3

  // ---- GEMM1: H[256,64] = W1s[256,384] * X[384,64] ----
  f32x4 acc[4][4] = {};
#pragma unroll
  for (int ks = 0; ks < 12; ++ks) {
    int k0 = ks * 32;
    s16x8 bfrag[4];
#pragma unroll
    for (int ct = 0; ct < 4; ++ct)
      bfrag[ct] = *(const s16x8*)&smem[(ct * 16 + lr) * XSTRIDE + k0 + lk * 8];
#pragma unroll
    for (int rt = 0; rt < 4; ++rt) {
      const s16x8 afrag = *(const s16x8*)&W1s[(size_t)(w * 64 + rt * 16 + lr) * 384 + k0 + lk * 8];
#pragma unroll
      for (int ct = 0; ct < 4; ++ct)
        acc[rt][ct] = __builtin_amdgcn_mfma_f32_16x16x32_bf16(afrag, bfrag[ct], acc[rt][ct], 0, 0, 0);
    }
  }
  __syncthreads();  // all X reads done -> smem may be reused as H

  // ---- bias + ReLU -> H bf16 in LDS (col-major) ----
#pragma unroll
  for (int rt = 0; rt < 4; ++rt) {
    int rowbase = w * 64 + rt * 16 + lk * 4;
    float c1v[4];
#pragma unroll
    for (int r = 0; r < 4; ++r) c1v[r] = c1[rowbase + r];
#pragma unroll
    for (int ct = 0; ct < 4; ++ct) {
      int col = ct * 16 + lr;
      float v0 = fmaxf(acc[rt][ct][0] + c1v[0], 0.f);
      float v1 = fmaxf(acc[rt][ct][1] + c1v[1], 0.f);
      float v2 = fmaxf(acc[rt][ct][2] + c1v[2], 0.f);
      float v3 = fmaxf(acc[rt][ct][3] + c1v[3], 0.f);
      unsigned int p0 = (unsigned int)f2bf(v0) | ((unsigned int)f2bf(v1) << 16);
      unsigned int p1 = (unsigned int)f2bf(v2) | ((unsigned int)f2bf(v3) << 16);
      *(uint2*)&smem[col * HSTRIDE + rowbase] = make_uint2(p0, p1);
    }
  }
  __syncthreads();

  // ---- GEMM2: U[128,64] = W2s[128,256] * H[256,64] ----
  f32x4 acc2[2][4] = {};
#pragma unroll
  for (int ks = 0; ks < 8; ++ks) {
    int k0 = ks * 32;
    s16x8 bfrag[4];
#pragma unroll
    for (int ct = 0; ct < 4; ++ct)
      bfrag[ct] = *(const s16x8*)&smem[(ct * 16 + lr) * HSTRIDE + k0 + lk * 8];
#pragma unroll
    for (int rt = 0; rt < 2; ++rt) {
      const s16x8 afrag = *(const s16x8*)&W2s[(size_t)(w * 32 + rt * 16 + lr) * 256 + k0 + lk * 8];
#pragma unroll
      for (int ct = 0; ct < 4; ++ct)
        acc2[rt][ct] = __builtin_amdgcn_mfma_f32_16x16x32_bf16(afrag, bfrag[ct], acc2[rt][ct], 0, 0, 0);
    }
  }

  // ---- epilogue: + b2, scatter-add ----
#pragma unroll
  for (int rt = 0; rt < 2; ++rt) {
    int rowbase = w * 32 + rt * 16 + lk * 4;
    float b2v[4];
#pragma unroll
    for (int r = 0; r < 4; ++r) b2v[r] = b2[rowbase + r];
#pragma unroll
    for (int ct = 0; ct < 4; ++ct) {
      int col = ct * 16 + lr;
      int n = idx_s[col];
      if (COAL) {
        // [n][d] layout: 128 dwords per column are contiguous -> 16 lines/instr
        float* dst = accout + (size_t)n * Dd + rowbase;
#pragma unroll
        for (int r = 0; r < 4; ++r)
          unsafeAtomicAdd(&dst[r], acc2[rt][ct][r] + b2v[r]);
      } else {
#pragma unroll
        for (int r = 0; r < 4; ++r)
          unsafeAtomicAdd(&accout[(size_t)(rowbase + r) * Nn + n], acc2[rt][ct][r] + b2v[r]);
      }
    }
  }
}

// ---- COAL finalize: out[sb][d][n] = ldesc[sb][d][n] + acc[sb][n][d]/max(cnt,1) ----
__global__ void finalize_coal(const float* __restrict__ l0, const float* __restrict__ l1,
                              const float* __restrict__ acc, const float* __restrict__ cnt,
                              float* __restrict__ out) {
  __shared__ float tile[32][33];
  __shared__ float cinv[32];
  int n0 = blockIdx.x * 32;
  int d0 = blockIdx.y * 32;
  int zb = blockIdx.z;           // side*4 + b
  int side = zb >> 2, b = zb & 3;
  int tx = threadIdx.x, ty = threadIdx.y;
  const float* accb = acc + (size_t)zb * Nn * Dd;
  const float* l = (side ? l1 : l0) + (size_t)b * Dd * Nn;
  float* o = out + (size_t)zb * Dd * Nn;

  if (ty == 0) cinv[tx] = 1.0f / fmaxf(cnt[(size_t)zb * Nn + n0 + tx], 1.0f);
#pragma unroll
  for (int i = 0; i < 4; ++i) {
    int nr = ty + i * 8;
    tile[nr][tx] = accb[(size_t)(n0 + nr) * Dd + d0 + tx];
  }
  __syncthreads();
#pragma unroll
  for (int i = 0; i < 4; ++i) {
    int d = d0 + ty + i * 8;
    size_t off = (size_t)d * Nn + n0 + tx;
    o[off] = l[off] + tile[tx][ty + i * 8] * cinv[tx];
  }
}

// ---- legacy finalize: out = ldesc + acc/max(cnt,1), in place over d_out ----
__global__ void finalize_kernel(const float* __restrict__ l0, const float* __restrict__ l1,
                                const float* __restrict__ cnt, float* __restrict__ out) {
  size_t i = (size_t)blockIdx.x * 256 + threadIdx.x;
  size_t base = i * 4;
  int n = (int)(base & (Nn - 1));
  size_t sbd = base >> 14;
  int d = (int)(sbd & (Dd - 1));
  int sb = (int)(sbd >> 7);
  int side = sb >> 2, b = sb & 3;
  const float* l = (side ? l1 : l0) + ((size_t)b * Dd + d) * Nn + n;
  float4 a = *(const float4*)&out[base];
  float4 c = *(const float4*)&cnt[(size_t)sb * Nn + n];
  float4 lv = *(const float4*)l;
  float4 r;
  r.x = lv.x + a.x / fmaxf(c.x, 1.f);
  r.y = lv.y + a.y / fmaxf(c.y, 1.f);
  r.z = lv.z + a.z / fmaxf(c.z, 1.f);
  r.w = lv.w + a.w / fmaxf(c.w, 1.f);
  *(float4*)&out[base] = r;
}

extern "C" void kernel_launch(void* const* d_in, const int* in_sizes, int n_in,
                              void* d_out, int out_size, void* d_ws, size_t ws_size,
                              hipStream_t stream) {
  const float* ldesc0 = (const float*)d_in[0];
  const float* ldesc1 = (const float*)d_in[1];
  const float* enc0   = (const float*)d_in[2];
  const float* enc1   = (const float*)d_in[3];
  const int*   idx0   = (const int*)d_in[4];
  const int*   idx1   = (const int*)d_in[5];
  const float* w1     = (const float*)d_in[6];
  const float* b1     = (const float*)d_in[7];
  const float* g      = (const float*)d_in[8];
  const float* beta   = (const float*)d_in[9];
  const float* mu     = (const float*)d_in[10];
  const float* var    = (const float*)d_in[11];
  const float* w2     = (const float*)d_in[12];
  const float* b2     = (const float*)d_in[13];
  float* out = (float*)d_out;

  char* ws = (char*)d_ws;
  size_t off = 0;
  unsigned short* t0 = (unsigned short*)(ws + off); off += (size_t)Bb * Nn * Dd * 2;
  unsigned short* t1 = (unsigned short*)(ws + off); off += (size_t)Bb * Nn * Dd * 2;
  unsigned short* W1s = (unsigned short*)(ws + off); off += 256 * 384 * 2;
  unsigned short* W2s = (unsigned short*)(ws + off); off += 128 * 256 * 2;
  float* c1 = (float*)(ws + off); off += 256 * 4;
  float* cnt = (float*)(ws + off); off += (size_t)2 * Bb * Nn * 4;
  float* acc = (float*)(ws + off);
  size_t need_coal = off + (size_t)2 * Bb * Dd * Nn * 4;

  hipMemsetAsync(cnt, 0, (size_t)2 * Bb * Nn * 4, stream);
  prep_weights<<<384, 256, 0, stream>>>(w1, b1, g, beta, mu, var, w2, W1s, W2s, c1);
  transpose_ldesc<<<dim3(Nn / 32, Dd / 32, 8), dim3(32, 8), 0, stream>>>(ldesc0, ldesc1, t0, t1);
  count_kernel<<<2048, 256, 0, stream>>>(idx0, idx1, cnt);

  if (ws_size >= need_coal) {
    hipMemsetAsync(acc, 0, (size_t)2 * Bb * Dd * Nn * 4, stream);
    fused_line_mlp<true><<<dim3(Ee / 64, Bb, 2), 256, 0, stream>>>(
        t0, t1, enc0, enc1, idx0, idx1, W1s, W2s, c1, b2, acc);
    finalize_coal<<<dim3(Nn / 32, Dd / 32, 8), dim3(32, 8), 0, stream>>>(
        ldesc0, ldesc1, acc, cnt, out);
  } else {
    hipMemsetAsync(out, 0, (size_t)2 * Bb * Dd * Nn * 4, stream);
    fused_line_mlp<false><<<dim3(Ee / 64, Bb, 2), 256, 0, stream>>>(
        t0, t1, enc0, enc1, idx0, idx1, W1s, W2s, c1, b2, out);
    finalize_kernel<<<16384, 256, 0, stream>>>(ldesc0, ldesc1, cnt, out);
  }
}

// Round 3
// 540.437 us; speedup vs baseline: 6.0290x; 1.8599x over previous
//
#include <hip/hip_runtime.h>
#include <hip/hip_bf16.h>
#include <stdint.h>

#define Bb 4
#define Dd 128
#define Nn 16384
#define Ee 65536

typedef __attribute__((ext_vector_type(4))) float f32x4;
typedef __attribute__((ext_vector_type(8))) short s16x8;

__device__ __forceinline__ unsigned short f2bf(float f) {
  union { float f; unsigned int u; } v; v.f = f;
  unsigned int r = v.u + 0x7fffu + ((v.u >> 16) & 1u);
  return (unsigned short)(r >> 16);
}

// ---- fold BN into weights, convert to bf16 ----
__global__ void prep_weights(const float* __restrict__ w1, const float* __restrict__ b1,
                             const float* __restrict__ g, const float* __restrict__ beta,
                             const float* __restrict__ mu, const float* __restrict__ var,
                             const float* __restrict__ w2,
                             unsigned short* __restrict__ W1s, unsigned short* __restrict__ W2s,
                             float* __restrict__ c1) {
  int i = blockIdx.x * 256 + threadIdx.x;
  if (i < 256 * 384) {
    int o = i / 384;
    float scale = g[o] * rsqrtf(var[o] + 1e-5f);
    W1s[i] = f2bf(w1[i] * scale);
  }
  if (i < 128 * 256) W2s[i] = f2bf(w2[i]);
  if (i < 256) {
    float scale = g[i] * rsqrtf(var[i] + 1e-5f);
    c1[i] = b1[i] * scale + beta[i] - mu[i] * scale;
  }
}

// ---- transpose one side: ldesc [B][D][N] f32 -> [B][N][D] bf16 ----
__global__ void transpose_side(const float* __restrict__ src, unsigned short* __restrict__ dst) {
  __shared__ float tile[32][33];
  int n0 = blockIdx.x * 32;
  int d0 = blockIdx.y * 32;
  int b = blockIdx.z;
  const float* s = src + (size_t)b * Dd * Nn;
  unsigned short* d = dst + (size_t)b * Nn * Dd;
  int tx = threadIdx.x, ty = threadIdx.y;
#pragma unroll
  for (int i = 0; i < 4; ++i)
    tile[ty + i * 8][tx] = s[(size_t)(d0 + ty + i * 8) * Nn + n0 + tx];
  __syncthreads();
#pragma unroll
  for (int i = 0; i < 4; ++i) {
    int r = ty + i * 8;
    d[(size_t)(n0 + r) * Dd + d0 + tx] = f2bf(tile[tx][r]);
  }
}

// ---- CSR build: histogram ----
__global__ void hist_kernel(const int* __restrict__ idx0, const int* __restrict__ idx1,
                            int* __restrict__ hist) {
  int i = blockIdx.x * 256 + threadIdx.x;  // 0 .. 2*B*E-1
  int sb = i >> 16;                        // side*4 + b
  int e = i & 65535;
  const int* jx = (sb >= 4) ? idx1 : idx0;
  int n = jx[(size_t)(sb & 3) * Ee + e];
  atomicAdd(&hist[sb * Nn + n], 1);
}

// ---- CSR build: per-sb exclusive scan of 16384 bins (8 blocks x 1024 thr) ----
__global__ __launch_bounds__(1024) void scan_kernel(const int* __restrict__ hist,
                                                    int* __restrict__ offs,
                                                    int* __restrict__ cursor) {
  __shared__ int part[1024];
  int sb = blockIdx.x, t = threadIdx.x;
  const int* h = hist + sb * Nn;
  int base = t * 16;
  int v[16];
  int local = 0;
#pragma unroll
  for (int i = 0; i < 16; ++i) { v[i] = local; local += h[base + i]; }
  part[t] = local;
  __syncthreads();
  for (int d = 1; d < 1024; d <<= 1) {
    int y = (t >= d) ? part[t - d] : 0;
    __syncthreads();
    part[t] += y;
    __syncthreads();
  }
  int excl = part[t] - local;
#pragma unroll
  for (int i = 0; i < 16; ++i) {
    int o = excl + v[i];
    offs[sb * Nn + base + i] = o;
    cursor[sb * Nn + base + i] = o;
  }
}

// ---- CSR build: fill entry lists ----
__global__ void fill_kernel(const int* __restrict__ idx0, const int* __restrict__ idx1,
                            int* __restrict__ cursor, int* __restrict__ elist) {
  int i = blockIdx.x * 256 + threadIdx.x;
  int sb = i >> 16;
  int e = i & 65535;
  const int* jx = (sb >= 4) ? idx1 : idx0;
  int n = jx[(size_t)(sb & 3) * Ee + e];
  int pos = atomicAdd(&cursor[sb * Nn + n], 1);
  elist[(size_t)sb * Ee + pos] = e;
}

#define XSTRIDE 392   // bf16 elems; 784 B row pitch
#define HSTRIDE 264   // bf16 elems; 528 B row pitch

// one side per launch: U[b][e][d] bf16 = MLP output (+b2), plain stores, no atomics
__global__ __launch_bounds__(256) void fused_line_mlp(
    const unsigned short* __restrict__ ldescT, const float* __restrict__ enc,
    const int* __restrict__ jx,
    const unsigned short* __restrict__ W1s, const unsigned short* __restrict__ W2s,
    const float* __restrict__ c1, const float* __restrict__ b2,
    unsigned short* __restrict__ U) {
  __shared__ unsigned short smem[64 * XSTRIDE];  // 50176 B; X tile, later aliased as H tile
  __shared__ int idx_s[64];

  const int b = blockIdx.y;
  const int e0 = blockIdx.x * 64;

  const int t = threadIdx.x;
  if (t < 64) idx_s[t] = jx[(size_t)b * Ee + e0 + t];
  __syncthreads();

  // ---- stage X = [desc(128); flipped(128); enc(128)] for 64 columns, bf16, col-major ----
  {
    int j = t >> 2, p = t & 3;
    int i0 = idx_s[j], i1 = idx_s[j ^ 1];
    const uint4* s0 = (const uint4*)(ldescT + ((size_t)b * Nn + i0) * Dd + p * 32);
    const uint4* s1 = (const uint4*)(ldescT + ((size_t)b * Nn + i1) * Dd + p * 32);
    uint4* dst0 = (uint4*)&smem[j * XSTRIDE + p * 32];
    uint4* dst1 = (uint4*)&smem[j * XSTRIDE + 128 + p * 32];
#pragma unroll
    for (int q = 0; q < 4; ++q) dst0[q] = s0[q];
#pragma unroll
    for (int q = 0; q < 4; ++q) dst1[q] = s1[q];
  }
  {
    int j = t & 63, dg = t >> 6;
    const float* src = enc + ((size_t)b * Dd + dg * 32) * Ee + e0 + j;
    unsigned int* dst = (unsigned int*)&smem[j * XSTRIDE + 256 + dg * 32];
#pragma unroll
    for (int d2 = 0; d2 < 32; d2 += 2) {
      float f0 = src[(size_t)d2 * Ee];
      float f1 = src[(size_t)(d2 + 1) * Ee];
      dst[d2 >> 1] = (unsigned int)f2bf(f0) | ((unsigned int)f2bf(f1) << 16);
    }
  }
  __syncthreads();

  const int w = t >> 6;          // wave 0..3
  const int lr = t & 15;         // row/col within 16-tile
  const int lk = (t & 63) >> 4;  // k-group 0..3

  // ---- GEMM1: H[256,64] = W1s[256,384] * X[384,64] ----
  f32x4 acc[4][4] = {};
#pragma unroll
  for (int ks = 0; ks < 12; ++ks) {
    int k0 = ks * 32;
    s16x8 bfrag[4];
#pragma unroll
    for (int ct = 0; ct < 4; ++ct)
      bfrag[ct] = *(const s16x8*)&smem[(ct * 16 + lr) * XSTRIDE + k0 + lk * 8];
#pragma unroll
    for (int rt = 0; rt < 4; ++rt) {
      const s16x8 afrag = *(const s16x8*)&W1s[(size_t)(w * 64 + rt * 16 + lr) * 384 + k0 + lk * 8];
#pragma unroll
      for (int ct = 0; ct < 4; ++ct)
        acc[rt][ct] = __builtin_amdgcn_mfma_f32_16x16x32_bf16(afrag, bfrag[ct], acc[rt][ct], 0, 0, 0);
    }
  }
  __syncthreads();  // all X reads done -> smem may be reused as H

  // ---- bias + ReLU -> H bf16 in LDS (col-major) ----
#pragma unroll
  for (int rt = 0; rt < 4; ++rt) {
    int rowbase = w * 64 + rt * 16 + lk * 4;
    float c1v[4];
#pragma unroll
    for (int r = 0; r < 4; ++r) c1v[r] = c1[rowbase + r];
#pragma unroll
    for (int ct = 0; ct < 4; ++ct) {
      int col = ct * 16 + lr;
      float v0 = fmaxf(acc[rt][ct][0] + c1v[0], 0.f);
      float v1 = fmaxf(acc[rt][ct][1] + c1v[1], 0.f);
      float v2 = fmaxf(acc[rt][ct][2] + c1v[2], 0.f);
      float v3 = fmaxf(acc[rt][ct][3] + c1v[3], 0.f);
      unsigned int p0 = (unsigned int)f2bf(v0) | ((unsigned int)f2bf(v1) << 16);
      unsigned int p1 = (unsigned int)f2bf(v2) | ((unsigned int)f2bf(v3) << 16);
      *(uint2*)&smem[col * HSTRIDE + rowbase] = make_uint2(p0, p1);
    }
  }
  __syncthreads();

  // ---- GEMM2: Uo[128,64] = W2s[128,256] * H[256,64] ----
  f32x4 acc2[2][4] = {};
#pragma unroll
  for (int ks = 0; ks < 8; ++ks) {
    int k0 = ks * 32;
    s16x8 bfrag[4];
#pragma unroll
    for (int ct = 0; ct < 4; ++ct)
      bfrag[ct] = *(const s16x8*)&smem[(ct * 16 + lr) * HSTRIDE + k0 + lk * 8];
#pragma unroll
    for (int rt = 0; rt < 2; ++rt) {
      const s16x8 afrag = *(const s16x8*)&W2s[(size_t)(w * 32 + rt * 16 + lr) * 256 + k0 + lk * 8];
#pragma unroll
      for (int ct = 0; ct < 4; ++ct)
        acc2[rt][ct] = __builtin_amdgcn_mfma_f32_16x16x32_bf16(afrag, bfrag[ct], acc2[rt][ct], 0, 0, 0);
    }
  }

  // ---- epilogue: + b2 -> bf16 U[b][e][d], plain coalesced-ish stores ----
#pragma unroll
  for (int rt = 0; rt < 2; ++rt) {
    int rowbase = w * 32 + rt * 16 + lk * 4;
    float b2v[4];
#pragma unroll
    for (int r = 0; r < 4; ++r) b2v[r] = b2[rowbase + r];
#pragma unroll
    for (int ct = 0; ct < 4; ++ct) {
      int col = ct * 16 + lr;
      float v0 = acc2[rt][ct][0] + b2v[0];
      float v1 = acc2[rt][ct][1] + b2v[1];
      float v2 = acc2[rt][ct][2] + b2v[2];
      float v3 = acc2[rt][ct][3] + b2v[3];
      uint2 pk;
      pk.x = (unsigned int)f2bf(v0) | ((unsigned int)f2bf(v1) << 16);
      pk.y = (unsigned int)f2bf(v2) | ((unsigned int)f2bf(v3) << 16);
      *(uint2*)&U[(((size_t)b * Ee + e0 + col) << 7) + rowbase] = pk;
    }
  }
}

// ---- scatter-mean + residual + transpose, one side per launch ----
// grid (Nn/64, Bb), block 256. Wave w handles junctions n0+w*16 .. +15.
__global__ __launch_bounds__(256) void scatter_finalize(
    const unsigned short* __restrict__ U, const int* __restrict__ elist_s,
    const int* __restrict__ offs_s, const float* __restrict__ ldesc_s,
    float* __restrict__ out_s) {
  __shared__ float lsum[64][129];
  const int b = blockIdx.y;
  const int n0 = blockIdx.x * 64;
  const int t = threadIdx.x;
  const int w = t >> 6, lane = t & 63;
  const unsigned int* Uu = (const unsigned int*)U;  // row = 64 uints (128 bf16)

#pragma unroll 1
  for (int q = 0; q < 16; ++q) {
    int jj = w * 16 + q;
    int n = n0 + jj;
    int s = offs_s[b * Nn + n];
    int e_end = (n == Nn - 1) ? Ee : offs_s[b * Nn + n + 1];
    float s0 = 0.f, s1 = 0.f;
    for (int k = s; k < e_end; ++k) {
      int e = elist_s[(size_t)b * Ee + k];
      unsigned int p = Uu[(((size_t)b * Ee + e) << 6) + lane];
      union { unsigned int u; float f; } lo, hi;
      lo.u = p << 16;
      hi.u = p & 0xffff0000u;
      s0 += lo.f;
      s1 += hi.f;
    }
    float inv = (e_end > s) ? 1.0f / (float)(e_end - s) : 0.0f;
    lsum[jj][lane * 2] = s0 * inv;
    lsum[jj][lane * 2 + 1] = s1 * inv;
  }
  __syncthreads();

  // write out[b][d][n] = ldesc[b][d][n] + lsum[n][d]; 64 consecutive n per instr
  int nloc = t & 63;
  int dbase = (t >> 6) * 32;
#pragma unroll
  for (int i = 0; i < 32; ++i) {
    int d = dbase + i;
    size_t o = (size_t)(b * Dd + d) * Nn + n0 + nloc;
    out_s[o] = ldesc_s[o] + lsum[nloc][d];
  }
}

extern "C" void kernel_launch(void* const* d_in, const int* in_sizes, int n_in,
                              void* d_out, int out_size, void* d_ws, size_t ws_size,
                              hipStream_t stream) {
  const float* ldesc0 = (const float*)d_in[0];
  const float* ldesc1 = (const float*)d_in[1];
  const float* enc0   = (const float*)d_in[2];
  const float* enc1   = (const float*)d_in[3];
  const int*   idx0   = (const int*)d_in[4];
  const int*   idx1   = (const int*)d_in[5];
  const float* w1     = (const float*)d_in[6];
  const float* b1     = (const float*)d_in[7];
  const float* g      = (const float*)d_in[8];
  const float* beta   = (const float*)d_in[9];
  const float* mu     = (const float*)d_in[10];
  const float* var    = (const float*)d_in[11];
  const float* w2     = (const float*)d_in[12];
  const float* b2     = (const float*)d_in[13];
  float* out = (float*)d_out;

  char* ws = (char*)d_ws;
  size_t off = 0;
  unsigned short* t   = (unsigned short*)(ws + off); off += (size_t)Bb * Nn * Dd * 2;  // 16.78 MB
  unsigned short* W1s = (unsigned short*)(ws + off); off += 256 * 384 * 2;
  unsigned short* W2s = (unsigned short*)(ws + off); off += 128 * 256 * 2;
  float* c1   = (float*)(ws + off); off += 256 * 4;
  int* hist   = (int*)(ws + off); off += (size_t)8 * Nn * 4;
  int* offs   = (int*)(ws + off); off += (size_t)8 * Nn * 4;
  int* cursor = (int*)(ws + off); off += (size_t)8 * Nn * 4;
  int* elist  = (int*)(ws + off); off += (size_t)8 * Ee * 4;
  unsigned short* U = (unsigned short*)(ws + off); off += (size_t)Bb * Ee * Dd * 2;    // 67.1 MB

  hipMemsetAsync(hist, 0, (size_t)8 * Nn * 4, stream);
  prep_weights<<<384, 256, 0, stream>>>(w1, b1, g, beta, mu, var, w2, W1s, W2s, c1);
  hist_kernel<<<2048, 256, 0, stream>>>(idx0, idx1, hist);
  scan_kernel<<<8, 1024, 0, stream>>>(hist, offs, cursor);
  fill_kernel<<<2048, 256, 0, stream>>>(idx0, idx1, cursor, elist);

  for (int side = 0; side < 2; ++side) {
    const float* ldesc_s = side ? ldesc1 : ldesc0;
    const float* enc_s = side ? enc1 : enc0;
    const int* jx = side ? idx1 : idx0;
    transpose_side<<<dim3(Nn / 32, Dd / 32, Bb), dim3(32, 8), 0, stream>>>(ldesc_s, t);
    fused_line_mlp<<<dim3(Ee / 64, Bb), 256, 0, stream>>>(t, enc_s, jx, W1s, W2s, c1, b2, U);
    scatter_finalize<<<dim3(Nn / 64, Bb), 256, 0, stream>>>(
        U, elist + (size_t)side * 4 * Ee, offs + (size_t)side * 4 * Nn,
        ldesc_s, out + (size_t)side * Bb * Dd * Nn);
  }
}